// Round 2
// baseline (863.725 us; speedup 1.0000x reference)
//
#include <hip/hip_runtime.h>
#include <hip/hip_fp16.h>

typedef _Float16 f16;
typedef _Float16 half8  __attribute__((ext_vector_type(8)));
typedef _Float16 half2v __attribute__((ext_vector_type(2)));
typedef float    floatx4 __attribute__((ext_vector_type(4)));

constexpr int SEQ  = 4096;   // L
constexpr int SEQP = 4098;   // L + 2 (zero pad row at each end per batch)

// ---------------------------------------------------------------------------
// async global->LDS, 16B per lane. ldsBase+off must be the WAVE-UNIFORM base;
// HW writes lane i to base + i*16. [learn_hip m97/m104]
__device__ __forceinline__ void dma16(const void* g, char* ldsBase, unsigned off) {
  __builtin_amdgcn_global_load_lds(
      (const __attribute__((address_space(1))) void*)g,
      (__attribute__((address_space(3))) void*)(ldsBase + off),
      16, 0, 0);
}

// ---------------------------------------------------------------------------
// GEMM over conv windows: C[r, n] = sum_k A[r, k] * W[k, n] + bias[n]
// A row r = contiguous 3*Cin window: A_elem(r,k) = A[b*bsA + (l0+r)*lda + k].
// Wt is W transposed: [N, K] row-major fp16.
// LDS swizzle: slot (r, c) holds global chunk (r, c ^ ((r>>1)&3)); kills the
// 8-way bank conflict of the unswizzled layout (2-way residual = free, m136).
// EPI: 0 = store f16; 1 = swish->f16; 2 = store f32;
//      3 = fused res+combine: store xco*softplus(delta)*cb*swish(acc+bias);
//      4 = dual store: cols<1024 -> Cp (delta), 1024..1055 -> Cp2 (bmcm[.,32])
template <int EPI>
__global__ __launch_bounds__(256, 2)
void gemm_k(const f16* __restrict__ A, const f16* __restrict__ Wt,
            const float* __restrict__ bias, void* __restrict__ Cp,
            void* __restrict__ Cp2, const f16* __restrict__ Edelta,
            const f16* __restrict__ Exco, const float* __restrict__ Ecb,
            int K, int lda, long batchStrideA,
            int ldc, long batchStrideC, int rowOff)
{
  __shared__ f16 lds[8192];          // A tile [128][32] | B tile [128][32]
  char* ldsB = (char*)lds;

  const int tid  = threadIdx.x;
  const int lane = tid & 63;
  const int wv   = tid >> 6;
  const int quad = lane >> 4;
  const int lr   = lane & 15;
  const int w_row = wv >> 1, w_col = wv & 1;

  const int r0 = blockIdx.x * 128;
  const int n0 = blockIdx.y * 128;
  const int b  = r0 >> 12;           // SEQ = 4096
  const int l0 = r0 & (SEQ - 1);

  const f16* Ab = A + (long)b * batchStrideA + (long)l0 * lda;

  // staging: 512 chunks of 16B per tile; this thread owns slots tid, tid+256.
  // slot s -> row s>>2, global column chunk (s&3) ^ ((s>>3)&3)  [swizzle]
  const int s0 = tid, s1 = tid + 256;
  const int r0s = s0 >> 2, c0s = ((s0 & 3) ^ ((s0 >> 3) & 3)) * 8;
  const int r1s = s1 >> 2, c1s = ((s1 & 3) ^ ((s1 >> 3) & 3)) * 8;
  const f16* gA0 = Ab + (long)r0s * lda + c0s;
  const f16* gA1 = Ab + (long)r1s * lda + c1s;
  const f16* gB0 = Wt + (long)(n0 + r0s) * K + c0s;
  const f16* gB1 = Wt + (long)(n0 + r1s) * K + c1s;
  const unsigned la0 = wv * 1024;            // wave-uniform LDS bases
  const unsigned la1 = 4096  + wv * 1024;
  const unsigned lb0 = 8192  + wv * 1024;
  const unsigned lb1 = 12288 + wv * 1024;

  floatx4 acc[4][4];
#pragma unroll
  for (int mi = 0; mi < 4; mi++)
#pragma unroll
    for (int ni = 0; ni < 4; ni++) acc[mi][ni] = (floatx4){0.f, 0.f, 0.f, 0.f};

  const int swz = (quad ^ ((lr >> 1) & 3)) * 8;   // read-side swizzle column

  for (int k0 = 0; k0 < K; k0 += 32) {
    __syncthreads();                 // previous iteration's reads done
    dma16(gA0 + k0, ldsB, la0);
    dma16(gA1 + k0, ldsB, la1);
    dma16(gB0 + k0, ldsB, lb0);
    dma16(gB1 + k0, ldsB, lb1);
    __syncthreads();                 // drains vmcnt, publishes LDS

    half8 af[4], bf[4];
#pragma unroll
    for (int mi = 0; mi < 4; mi++)
      af[mi] = *(const half8*)&lds[(w_row * 64 + mi * 16 + lr) * 32 + swz];
#pragma unroll
    for (int ni = 0; ni < 4; ni++)
      bf[ni] = *(const half8*)&lds[4096 + (w_col * 64 + ni * 16 + lr) * 32 + swz];

#pragma unroll
    for (int mi = 0; mi < 4; mi++)
#pragma unroll
      for (int ni = 0; ni < 4; ni++)
        acc[mi][ni] = __builtin_amdgcn_mfma_f32_16x16x32_f16(af[mi], bf[ni], acc[mi][ni], 0, 0, 0);
  }

  // epilogue: C/D layout col=lane&15, row=quad*4+reg  [learn_hip m89]
  const int colBase = n0 + w_col * 64 + lr;
  float bv[4];
#pragma unroll
  for (int ni = 0; ni < 4; ni++) bv[ni] = bias[colBase + ni * 16];

  const long cbb = (long)b * batchStrideC;
#pragma unroll
  for (int mi = 0; mi < 4; mi++) {
#pragma unroll
    for (int i = 0; i < 4; i++) {
      const int rl = w_row * 64 + mi * 16 + quad * 4 + i;
      const long rowFlat = cbb + (long)(l0 + rl + rowOff) * ldc;
      const int rg = r0 + rl;                     // global unpadded row
#pragma unroll
      for (int ni = 0; ni < 4; ni++) {
        const int c = colBase + ni * 16;
        float v = acc[mi][ni][i] + bv[ni];
        if (EPI == 0) {
          ((f16*)Cp)[rowFlat + c] = (f16)v;
        } else if (EPI == 1) {
          v = v / (1.f + expf(-v));
          ((f16*)Cp)[rowFlat + c] = (f16)v;
        } else if (EPI == 2) {
          ((float*)Cp)[rowFlat + c] = v;
        } else if (EPI == 3) {
          v = v / (1.f + expf(-v));               // x_res = swish(conv(xn,res))
          float d  = (float)Edelta[(long)rg * 1024 + c];
          float sp = d > 20.f ? d : log1pf(expf(d));
          float xc = (float)Exco[rowFlat + c];    // xco shares padded layout
          ((f16*)Cp)[rowFlat + c] = (f16)(xc * sp * Ecb[rg] * v);
        } else {  // EPI == 4
          if (c < 1024)      ((f16*)Cp)[rowFlat + c] = (f16)v;
          else if (c < 1056) ((f16*)Cp2)[(long)rg * 32 + (c - 1024)] = (f16)v;
        }
      }
    }
  }
}

// ---------------------------------------------------------------------------
// all 6 weight transposes in one launch: w [K,N] f32 -> wt [N,K] f16
__global__ __launch_bounds__(256)
void wt_all(const float* __restrict__ s0, const float* __restrict__ s1,
            const float* __restrict__ s2, const float* __restrict__ s3,
            const float* __restrict__ s4, const float* __restrict__ s5,
            f16* d0, f16* d1, f16* d2, f16* d3, f16* d4, f16* d5)
{
  const float* src; f16* dst; int K, N;
  switch (blockIdx.y) {
    case 0:  src = s0; dst = d0; K = 1536; N = 1024; break;
    case 1:  src = s1; dst = d1; K = 3072; N = 1024; break;
    case 2:  src = s2; dst = d2; K = 3072; N = 1024; break;
    case 3:  src = s3; dst = d3; K = 3072; N = 1024; break;
    case 4:  src = s4; dst = d4; K = 1536; N = 1024; break;
    default: src = s5; dst = d5; K = 3072; N = 512;  break;
  }
  const int ktiles = K >> 5;
  const int t = blockIdx.x;
  if (t >= ktiles * (N >> 5)) return;
  const int kt = (t % ktiles) * 32, nt = (t / ktiles) * 32;

  __shared__ float tile[32][33];
  const int tx = threadIdx.x & 31, ty = threadIdx.x >> 5;
#pragma unroll
  for (int i = 0; i < 32; i += 8)
    tile[ty + i][tx] = src[(long)(kt + ty + i) * N + nt + tx];
  __syncthreads();
#pragma unroll
  for (int i = 0; i < 32; i += 8)
    dst[(long)(nt + ty + i) * K + kt + tx] = (f16)tile[tx][ty + i];
}

// fc2|fc3 concat, zero-padded to 128 rows of the combined Wt: wt [128,3072] f16
__global__ void fc23_build(const float* __restrict__ fc2, const float* __restrict__ fc3,
                           f16* __restrict__ wt)
{
  int idx = blockIdx.x * 256 + threadIdx.x;   // over 128*3072
  int n = idx / 3072, k = idx - n * 3072;
  float v = 0.f;
  if (n < 16)      v = fc2[k * 16 + n];
  else if (n < 32) v = fc3[k * 16 + n - 16];
  wt[idx] = (f16)v;
}

// combined bias for the N=1152 fc1|fc2|fc3 GEMM
__global__ void bias_build(const float* __restrict__ b1, const float* __restrict__ b2,
                           const float* __restrict__ b3, float* __restrict__ bo)
{
  int t = blockIdx.x * 256 + threadIdx.x;
  if (t >= 1152) return;
  float v = 0.f;
  if (t < 1024)      v = b1[t];
  else if (t < 1040) v = b2[t - 1024];
  else if (t < 1056) v = b3[t - 1040];
  bo[t] = v;
}

// zero the padding rows (p=0 and p=SEQP-1 per batch) of the 4 padded buffers
__global__ void zero_pads(f16* xn, f16* xproj, f16* xconv, f16* xco)
{
  int b = blockIdx.x >> 1, e = blockIdx.x & 1;
  f16* base; int C;
  switch (blockIdx.y) {
    case 0:  base = xn;    C = 512;  break;
    case 1:  base = xproj; C = 1024; break;
    case 2:  base = xconv; C = 1024; break;
    default: base = xco;   C = 1024; break;
  }
  long p = e ? (SEQP - 1) : 0;
  f16* row = base + ((long)b * SEQP + p) * C;
  for (int c = threadIdx.x; c < C; c += 256) row[c] = (f16)0;
}

// rmsnorm over D=512, fp32 in -> fp16 padded out
__global__ __launch_bounds__(256)
void rmsnorm_k(const float* __restrict__ x, const float* __restrict__ nw,
               f16* __restrict__ xn)
{
  const int row = blockIdx.x;             // 0..16383
  const int b = row >> 12, l = row & (SEQ - 1);
  const int t = threadIdx.x;
  float2 v = ((const float2*)(x + (long)row * 512))[t];
  float ss = v.x * v.x + v.y * v.y;
#pragma unroll
  for (int o = 32; o > 0; o >>= 1) ss += __shfl_down(ss, o, 64);
  __shared__ float sred[4];
  if ((t & 63) == 0) sred[t >> 6] = ss;
  __syncthreads();
  float tot = sred[0] + sred[1] + sred[2] + sred[3];
  float rs = rsqrtf(tot * (1.f / 512.f) + 1e-5f);
  float2 w = ((const float2*)nw)[t];
  half2v o2;
  o2.x = (f16)(v.x * rs * w.x);
  o2.y = (f16)(v.y * rs * w.y);
  ((half2v*)(xn + ((long)b * SEQP + l + 1) * 512))[t] = o2;
}

// cb[r] = sum_16 Bm[r,n]*Cm[r,n]   (bmcm row = [Bm(16) | Cm(16)] f16)
__global__ __launch_bounds__(256)
void cb_k(const f16* __restrict__ bmcm, float* __restrict__ cb)
{
  int r = blockIdx.x * 256 + threadIdx.x;     // 16384 rows
  const half8* p = (const half8*)(bmcm + (long)r * 32);
  half8 b0 = p[0], b1 = p[1], c0 = p[2], c1 = p[3];
  float s = 0.f;
#pragma unroll
  for (int j = 0; j < 8; j++)
    s += (float)b0[j] * (float)c0[j] + (float)b1[j] * (float)c1[j];
  cb[r] = s;
}

// ---------------------------------------------------------------------------
extern "C" void kernel_launch(void* const* d_in, const int* in_sizes, int n_in,
                              void* d_out, int out_size, void* d_ws, size_t ws_size,
                              hipStream_t stream)
{
  const float* x      = (const float*)d_in[0];
  const float* norm_w = (const float*)d_in[1];
  const float* inp_w  = (const float*)d_in[2];
  const float* inp_b  = (const float*)d_in[3];
  const float* conv_w = (const float*)d_in[4];
  const float* conv_b = (const float*)d_in[5];
  const float* cl_w   = (const float*)d_in[6];
  const float* cl_b   = (const float*)d_in[7];
  const float* fc1_w  = (const float*)d_in[8];
  const float* fc1_b  = (const float*)d_in[9];
  const float* fc2_w  = (const float*)d_in[10];
  const float* fc2_b  = (const float*)d_in[11];
  const float* fc3_w  = (const float*)d_in[12];
  const float* fc3_b  = (const float*)d_in[13];
  // d_in[14] = A: provably unused (dA multiplies a zero initial state)
  const float* res_w  = (const float*)d_in[15];
  const float* res_b  = (const float*)d_in[16];
  const float* out_w  = (const float*)d_in[17];
  const float* out_b  = (const float*)d_in[18];

  char* ws = (char*)d_ws;
  size_t off = 0;
  auto alloc = [&](size_t bytes) -> char* {
    char* p = ws + off; off += (bytes + 511) & ~(size_t)511; return p;
  };
  f16* Wt_inp   = (f16*)alloc(1024ull * 1536 * 2);
  f16* Wt_conv  = (f16*)alloc(1024ull * 3072 * 2);
  f16* Wt_cl    = (f16*)alloc(1024ull * 3072 * 2);
  f16* Wt_fc1x  = (f16*)alloc(1152ull * 3072 * 2);   // fc1 | fc2 | fc3 | zeros
  f16* Wt_res   = (f16*)alloc(1024ull * 1536 * 2);
  f16* Wt_out   = (f16*)alloc(512ull  * 3072 * 2);
  float* b_fc1x = (float*)alloc(1152 * 4);
  f16* xn_pad    = (f16*)alloc(4ull * SEQP * 512  * 2);
  f16* xproj_pad = (f16*)alloc(4ull * SEQP * 1024 * 2);  // later reused as prod_pad
  f16* xconv_pad = (f16*)alloc(4ull * SEQP * 1024 * 2);  // later reused as delta_pre
  f16* xco_pad   = (f16*)alloc(4ull * SEQP * 1024 * 2);
  f16* bmcm      = (f16*)alloc(16384ull * 32 * 2);
  float* cb      = (float*)alloc(16384ull * 4);

  // --- weight prep (reruns every launch: ws is re-poisoned) ---
  wt_all<<<dim3(3072, 6), 256, 0, stream>>>(inp_w, conv_w, cl_w, fc1_w, res_w, out_w,
                                            Wt_inp, Wt_conv, Wt_cl, Wt_fc1x, Wt_res, Wt_out);
  fc23_build<<<1536, 256, 0, stream>>>(fc2_w, fc3_w, Wt_fc1x + 1024ull * 3072);
  bias_build<<<5, 256, 0, stream>>>(fc1_b, fc2_b, fc3_b, b_fc1x);
  zero_pads<<<dim3(8, 4), 256, 0, stream>>>(xn_pad, xproj_pad, xconv_pad, xco_pad);

  // --- pipeline ---
  rmsnorm_k<<<16384, 256, 0, stream>>>(x, norm_w, xn_pad);

  // x_proj = conv(xn, inp)                      [K=1536 -> N=1024, padded out]
  gemm_k<0><<<dim3(128, 8), 256, 0, stream>>>(xn_pad, Wt_inp, inp_b, xproj_pad,
      nullptr, nullptr, nullptr, nullptr,
      1536, 512, (long)SEQP * 512, 1024, (long)SEQP * 1024, 1);
  // x_conv = swish(conv(x_proj, conv))          [3072 -> 1024, padded]
  gemm_k<1><<<dim3(128, 8), 256, 0, stream>>>(xproj_pad, Wt_conv, conv_b, xconv_pad,
      nullptr, nullptr, nullptr, nullptr,
      3072, 1024, (long)SEQP * 1024, 1024, (long)SEQP * 1024, 1);
  // x_conv_out = conv(x_conv, cl)               [3072 -> 1024, padded]
  gemm_k<0><<<dim3(128, 8), 256, 0, stream>>>(xconv_pad, Wt_cl, cl_b, xco_pad,
      nullptr, nullptr, nullptr, nullptr,
      3072, 1024, (long)SEQP * 1024, 1024, (long)SEQP * 1024, 1);
  // delta_pre | Bm | Cm = conv(xco, fc1|fc2|fc3)  [3072 -> 1152, unpadded]
  f16* delta_pre = xconv_pad;                     // aliases (xconv consumed)
  gemm_k<4><<<dim3(128, 9), 256, 0, stream>>>(xco_pad, Wt_fc1x, b_fc1x, delta_pre,
      bmcm, nullptr, nullptr, nullptr,
      3072, 1024, (long)SEQP * 1024, 1024, (long)SEQ * 1024, 0);
  // cb = dot(Bm, Cm) per row
  cb_k<<<64, 256, 0, stream>>>(bmcm, cb);
  // prod = xco * softplus(delta) * cb * swish(conv(xn,res))   [padded out]
  f16* prod_pad = xproj_pad;                      // aliases (xproj consumed)
  gemm_k<3><<<dim3(128, 8), 256, 0, stream>>>(xn_pad, Wt_res, res_b, prod_pad,
      nullptr, delta_pre, xco_pad, cb,
      1536, 512, (long)SEQP * 512, 1024, (long)SEQP * 1024, 1);
  // out = conv(prod, out)                       [3072 -> 512, fp32 -> d_out]
  gemm_k<2><<<dim3(128, 4), 256, 0, stream>>>(prod_pad, Wt_out, out_b, d_out,
      nullptr, nullptr, nullptr, nullptr,
      3072, 1024, (long)SEQP * 1024, 512, (long)SEQ * 512, 0);
}

// Round 3
// 723.937 us; speedup vs baseline: 1.1931x; 1.1931x over previous
//
#include <hip/hip_runtime.h>
#include <hip/hip_fp16.h>

typedef _Float16 f16;
typedef _Float16 half8  __attribute__((ext_vector_type(8)));
typedef _Float16 half4v __attribute__((ext_vector_type(4)));
typedef _Float16 half2v __attribute__((ext_vector_type(2)));
typedef float    floatx4 __attribute__((ext_vector_type(4)));

constexpr int SEQ  = 4096;   // L
constexpr int SEQP = 4098;   // L + 2 (zero pad row at each end per batch)

// ---------------------------------------------------------------------------
// async global->LDS, 16B per lane. ldsBase+off must be the WAVE-UNIFORM base;
// HW writes lane i to base + i*16. [learn_hip m97/m104]
__device__ __forceinline__ void dma16(const void* g, char* ldsBase, unsigned off) {
  __builtin_amdgcn_global_load_lds(
      (const __attribute__((address_space(1))) void*)g,
      (__attribute__((address_space(3))) void*)(ldsBase + off),
      16, 0, 0);
}

// ---------------------------------------------------------------------------
// GEMM over conv windows, BK=64: C[r,n] = sum_k A[r,k]*W[k,n] + bias[n]
// A row r = contiguous 3*Cin window: A_elem(r,k) = A[b*bsA + (l0+r)*lda + k].
// Wt is W transposed: [N, ldb] row-major fp16 (ldb = total K).
// LDS tile row = 64 f16 = 8 chunks of 16B; slot (r,c) holds global chunk
// c ^ (r&7)  -> read-side 2-way residual only (free, m136).
// kSlice: K covered per z-slice (== total K when gridDim.z == 1).
// EPI: 0 f16 store; 1 swish->f16; 2 f32 store;
//      5 inp|res dual: c<1024 -> Cp (padded, rowOff=1), else swish -> Cp2 [SEQ*1024]
//      6 split-K bmcm: c<32 -> atomicAdd f32 Cp[rg*32+c] (bias only on z==0)
template <int EPI>
__global__ __launch_bounds__(256, 2)
void gemm_k(const f16* __restrict__ A, const f16* __restrict__ Wt,
            const float* __restrict__ bias, void* __restrict__ Cp,
            void* __restrict__ Cp2,
            int kSlice, int lda, long bsA, int ldb,
            int ldc, long bsC, int rowOff)
{
  __shared__ f16 lds[16384];         // A tile [128][64] | B tile [128][64]
  char* ldsB = (char*)lds;

  const int tid  = threadIdx.x;
  const int lane = tid & 63;
  const int wv   = tid >> 6;
  const int quad = lane >> 4;
  const int lr   = lane & 15;
  const int w_row = wv >> 1, w_col = wv & 1;

  const int r0 = blockIdx.x * 128;
  const int n0 = blockIdx.y * 128;
  const int b  = r0 >> 12;           // SEQ = 4096
  const int l0 = r0 & (SEQ - 1);
  const int kBeg = blockIdx.z * kSlice;

  // staging: thread t owns slots {j*256+t}: row = j*32 + (t>>3),
  // global chunk = (t&7) ^ ((t>>3)&7)   (j*32 mod 8 == 0)
  const int trow   = tid >> 3;
  const int tchunk = ((tid & 7) ^ ((tid >> 3) & 7)) * 8;     // f16 elems
  const f16* gA = A + (long)b * bsA + (long)(l0 + trow) * lda + kBeg + tchunk;
  const f16* gB = Wt + (long)(n0 + trow) * ldb + kBeg + tchunk;
  const long stepA = 32l * lda, stepB = 32l * ldb;

  floatx4 acc[4][4];
#pragma unroll
  for (int mi = 0; mi < 4; mi++)
#pragma unroll
    for (int ni = 0; ni < 4; ni++) acc[mi][ni] = (floatx4){0.f, 0.f, 0.f, 0.f};

  // read-side swizzle: row&7 == lr&7 for all frag rows (strides mult. of 8)
  const int colx = (quad ^ (lr & 7)) * 8;    // f16 elems, k-step 0

  for (int k0 = 0; k0 < kSlice; k0 += 64) {
    __syncthreads();                 // previous iteration's reads done
#pragma unroll
    for (int j = 0; j < 4; j++) {
      dma16(gA + k0 + j * stepA, ldsB,         j * 4096 + wv * 1024);
      dma16(gB + k0 + j * stepB, ldsB, 16384 + j * 4096 + wv * 1024);
    }
    __syncthreads();                 // drains vmcnt, publishes LDS

#pragma unroll
    for (int s = 0; s < 2; s++) {
      const int cs = colx ^ (s * 32);
      half8 af[4], bf[4];
#pragma unroll
      for (int mi = 0; mi < 4; mi++)
        af[mi] = *(const half8*)&lds[(w_row * 64 + mi * 16 + lr) * 64 + cs];
#pragma unroll
      for (int ni = 0; ni < 4; ni++)
        bf[ni] = *(const half8*)&lds[8192 + (w_col * 64 + ni * 16 + lr) * 64 + cs];
#pragma unroll
      for (int mi = 0; mi < 4; mi++)
#pragma unroll
        for (int ni = 0; ni < 4; ni++)
          acc[mi][ni] = __builtin_amdgcn_mfma_f32_16x16x32_f16(af[mi], bf[ni], acc[mi][ni], 0, 0, 0);
    }
  }

  // epilogue: C/D layout col=lane&15, row=quad*4+reg  [learn_hip m89]
  const int colBase = n0 + w_col * 64 + lr;
  float bv[4];
#pragma unroll
  for (int ni = 0; ni < 4; ni++)
    bv[ni] = (EPI == 6 && blockIdx.z != 0) ? 0.f : bias[colBase + ni * 16];

  const long cbb = (long)b * bsC;
#pragma unroll
  for (int mi = 0; mi < 4; mi++) {
#pragma unroll
    for (int i = 0; i < 4; i++) {
      const int rl = w_row * 64 + mi * 16 + quad * 4 + i;
      const long rowFlat = cbb + (long)(l0 + rl + rowOff) * ldc;
      const int rg = r0 + rl;                     // global unpadded row
#pragma unroll
      for (int ni = 0; ni < 4; ni++) {
        const int c = colBase + ni * 16;
        float v = acc[mi][ni][i] + bv[ni];
        if (EPI == 0) {
          ((f16*)Cp)[rowFlat + c] = (f16)v;
        } else if (EPI == 1) {
          v = v / (1.f + expf(-v));
          ((f16*)Cp)[rowFlat + c] = (f16)v;
        } else if (EPI == 2) {
          ((float*)Cp)[rowFlat + c] = v;
        } else if (EPI == 5) {
          if (c < 1024) {            // x_proj (padded layout, rowOff=1)
            ((f16*)Cp)[cbb + (long)(l0 + rl + 1) * 1024 + c] = (f16)v;
          } else {                   // x_res = swish(...), unpadded
            v = v / (1.f + expf(-v));
            ((f16*)Cp2)[(long)rg * 1024 + (c - 1024)] = (f16)v;
          }
        } else {  // EPI == 6
          if (c < 32) atomicAdd((float*)Cp + (long)rg * 32 + c, v);
        }
      }
    }
  }
}

// ---------------------------------------------------------------------------
// all 6 weight transposes in one launch: w [K,N] f32 -> wt [N,K] f16
__global__ __launch_bounds__(256)
void wt_all(const float* __restrict__ s0, const float* __restrict__ s1,
            const float* __restrict__ s2, const float* __restrict__ s3,
            const float* __restrict__ s4, const float* __restrict__ s5,
            f16* d0, f16* d1, f16* d2, f16* d3, f16* d4, f16* d5)
{
  const float* src; f16* dst; int K, N;
  switch (blockIdx.y) {
    case 0:  src = s0; dst = d0; K = 1536; N = 1024; break;   // inp
    case 1:  src = s1; dst = d1; K = 3072; N = 1024; break;   // conv
    case 2:  src = s2; dst = d2; K = 3072; N = 1024; break;   // cl
    case 3:  src = s3; dst = d3; K = 3072; N = 1024; break;   // fc1
    case 4:  src = s4; dst = d4; K = 1536; N = 1024; break;   // res
    default: src = s5; dst = d5; K = 3072; N = 512;  break;   // out
  }
  const int ktiles = K >> 5;
  const int t = blockIdx.x;
  if (t >= ktiles * (N >> 5)) return;
  const int kt = (t % ktiles) * 32, nt = (t / ktiles) * 32;

  __shared__ float tile[32][33];
  const int tx = threadIdx.x & 31, ty = threadIdx.x >> 5;
#pragma unroll
  for (int i = 0; i < 32; i += 8)
    tile[ty + i][tx] = src[(long)(kt + ty + i) * N + nt + tx];
  __syncthreads();
#pragma unroll
  for (int i = 0; i < 32; i += 8)
    dst[(long)(nt + ty + i) * K + kt + tx] = (f16)tile[tx][ty + i];
}

// fc2|fc3 concat, zero-padded to 128 rows: wt [128,3072] f16
__global__ void fc23_build(const float* __restrict__ fc2, const float* __restrict__ fc3,
                           f16* __restrict__ wt)
{
  int idx = blockIdx.x * 256 + threadIdx.x;   // over 128*3072
  int n = idx / 3072, k = idx - n * 3072;
  float v = 0.f;
  if (n < 16)      v = fc2[k * 16 + n];
  else if (n < 32) v = fc3[k * 16 + n - 16];
  wt[idx] = (f16)v;
}

// biases: b_inpres[2048] = inp_b|res_b ; b_fc23[128] = fc2_b|fc3_b|0
__global__ void bias_build(const float* __restrict__ bi, const float* __restrict__ br,
                           const float* __restrict__ b2, const float* __restrict__ b3,
                           float* __restrict__ b_inpres, float* __restrict__ b_fc23)
{
  int t = blockIdx.x * 256 + threadIdx.x;
  if (t < 1024)      b_inpres[t] = bi[t];
  else if (t < 2048) b_inpres[t] = br[t - 1024];
  else if (t < 2176) {
    int u = t - 2048;
    b_fc23[u] = u < 16 ? b2[u] : (u < 32 ? b3[u - 16] : 0.f);
  }
}

// zero the padding rows (p=0 and p=SEQP-1 per batch) of the 4 padded buffers
__global__ void zero_pads(f16* xn, f16* xproj, f16* xconv, f16* xco)
{
  int b = blockIdx.x >> 1, e = blockIdx.x & 1;
  f16* base; int C;
  switch (blockIdx.y) {
    case 0:  base = xn;    C = 512;  break;
    case 1:  base = xproj; C = 1024; break;
    case 2:  base = xconv; C = 1024; break;
    default: base = xco;   C = 1024; break;
  }
  long p = e ? (SEQP - 1) : 0;
  f16* row = base + ((long)b * SEQP + p) * C;
  for (int c = threadIdx.x; c < C; c += 256) row[c] = (f16)0;
}

// zero bmcmF accumulator (16384*32 f32 = 524288 floats)
__global__ void zero_f32(float4* p)
{
  p[blockIdx.x * 256 + threadIdx.x] = (float4){0.f, 0.f, 0.f, 0.f};
}

// rmsnorm over D=512, fp32 in -> fp16 padded out
__global__ __launch_bounds__(256)
void rmsnorm_k(const float* __restrict__ x, const float* __restrict__ nw,
               f16* __restrict__ xn)
{
  const int row = blockIdx.x;             // 0..16383
  const int b = row >> 12, l = row & (SEQ - 1);
  const int t = threadIdx.x;
  float2 v = ((const float2*)(x + (long)row * 512))[t];
  float ss = v.x * v.x + v.y * v.y;
#pragma unroll
  for (int o = 32; o > 0; o >>= 1) ss += __shfl_down(ss, o, 64);
  __shared__ float sred[4];
  if ((t & 63) == 0) sred[t >> 6] = ss;
  __syncthreads();
  float tot = sred[0] + sred[1] + sred[2] + sred[3];
  float rs = rsqrtf(tot * (1.f / 512.f) + 1e-5f);
  float2 w = ((const float2*)nw)[t];
  half2v o2;
  o2.x = (f16)(v.x * rs * w.x);
  o2.y = (f16)(v.y * rs * w.y);
  ((half2v*)(xn + ((long)b * SEQP + l + 1) * 512))[t] = o2;
}

// prod = xco * softplus(delta) * cb * xres;  cb computed in-block from bmcmF
__global__ __launch_bounds__(256)
void combine_k(const f16* __restrict__ delta_pre, const f16* __restrict__ xco_pad,
               const float* __restrict__ bmcmF, const f16* __restrict__ xres,
               f16* __restrict__ prod_pad)
{
  const int row = blockIdx.x;
  const int b = row >> 12, l = row & (SEQ - 1);
  const int t = threadIdx.x;
  __shared__ float cb_s;
  if (t < 16) {
    float p = bmcmF[(long)row * 32 + t] * bmcmF[(long)row * 32 + 16 + t];
#pragma unroll
    for (int o = 8; o > 0; o >>= 1) p += __shfl_down(p, o, 64);
    if (t == 0) cb_s = p;
  }
  __syncthreads();
  const float cb = cb_s;
  const long urow = (long)row * 1024;
  const long prow = ((long)b * SEQP + l + 1) * 1024;
  half4v dp = ((const half4v*)(delta_pre + urow))[t];
  half4v xc = ((const half4v*)(xco_pad + prow))[t];
  half4v xr = ((const half4v*)(xres + urow))[t];
  half4v o;
#pragma unroll
  for (int j = 0; j < 4; j++) {
    float d  = (float)dp[j];
    float sp = d > 20.f ? d : log1pf(expf(d));     // softplus
    o[j] = (f16)((float)xc[j] * sp * cb * (float)xr[j]);
  }
  ((half4v*)(prod_pad + prow))[t] = o;
}

// ---------------------------------------------------------------------------
extern "C" void kernel_launch(void* const* d_in, const int* in_sizes, int n_in,
                              void* d_out, int out_size, void* d_ws, size_t ws_size,
                              hipStream_t stream)
{
  const float* x      = (const float*)d_in[0];
  const float* norm_w = (const float*)d_in[1];
  const float* inp_w  = (const float*)d_in[2];
  const float* inp_b  = (const float*)d_in[3];
  const float* conv_w = (const float*)d_in[4];
  const float* conv_b = (const float*)d_in[5];
  const float* cl_w   = (const float*)d_in[6];
  const float* cl_b   = (const float*)d_in[7];
  const float* fc1_w  = (const float*)d_in[8];
  const float* fc1_b  = (const float*)d_in[9];
  const float* fc2_w  = (const float*)d_in[10];
  const float* fc2_b  = (const float*)d_in[11];
  const float* fc3_w  = (const float*)d_in[12];
  const float* fc3_b  = (const float*)d_in[13];
  // d_in[14] = A: provably unused (dA multiplies a zero initial state)
  const float* res_w  = (const float*)d_in[15];
  const float* res_b  = (const float*)d_in[16];
  const float* out_w  = (const float*)d_in[17];
  const float* out_b  = (const float*)d_in[18];

  char* ws = (char*)d_ws;
  size_t off = 0;
  auto alloc = [&](size_t bytes) -> char* {
    char* p = ws + off; off += (bytes + 511) & ~(size_t)511; return p;
  };
  f16* Wt_inpres = (f16*)alloc(2048ull * 1536 * 2);  // inp rows 0-1023 | res rows 1024-2047
  f16* Wt_conv   = (f16*)alloc(1024ull * 3072 * 2);
  f16* Wt_cl     = (f16*)alloc(1024ull * 3072 * 2);
  f16* Wt_fc1    = (f16*)alloc(1024ull * 3072 * 2);
  f16* Wt_fc23   = (f16*)alloc(128ull  * 3072 * 2);
  f16* Wt_out    = (f16*)alloc(512ull  * 3072 * 2);
  float* b_inpres = (float*)alloc(2048 * 4);
  float* b_fc23   = (float*)alloc(128 * 4);
  f16* xn_pad    = (f16*)alloc(4ull * SEQP * 512  * 2);
  f16* xproj_pad = (f16*)alloc(4ull * SEQP * 1024 * 2);  // later reused as prod_pad
  f16* xconv_pad = (f16*)alloc(4ull * SEQP * 1024 * 2);  // later reused as delta_pre
  f16* xco_pad   = (f16*)alloc(4ull * SEQP * 1024 * 2);
  f16* xres      = (f16*)alloc(16384ull * 1024 * 2);
  float* bmcmF   = (float*)alloc(16384ull * 32 * 4);

  // --- prep (reruns every launch: ws is re-poisoned) ---
  wt_all<<<dim3(3072, 6), 256, 0, stream>>>(inp_w, conv_w, cl_w, fc1_w, res_w, out_w,
      Wt_inpres, Wt_conv, Wt_cl, Wt_fc1, Wt_inpres + 1024ull * 1536, Wt_out);
  fc23_build<<<1536, 256, 0, stream>>>(fc2_w, fc3_w, Wt_fc23);
  bias_build<<<9, 256, 0, stream>>>(inp_b, res_b, fc2_b, fc3_b, b_inpres, b_fc23);
  zero_pads<<<dim3(8, 4), 256, 0, stream>>>(xn_pad, xproj_pad, xconv_pad, xco_pad);
  zero_f32<<<512, 256, 0, stream>>>((float4*)bmcmF);

  // --- pipeline ---
  rmsnorm_k<<<16384, 256, 0, stream>>>(x, norm_w, xn_pad);

  // x_proj | x_res_pre: conv(xn, inp|res)     [K=1536 -> N=2048, grid 2048]
  gemm_k<5><<<dim3(128, 16), 256, 0, stream>>>(xn_pad, Wt_inpres, b_inpres,
      xproj_pad, xres, 1536, 512, (long)SEQP * 512, 1536, 1024, (long)SEQP * 1024, 1);
  // x_conv = swish(conv(x_proj, conv))        [3072 -> 1024, padded]
  gemm_k<1><<<dim3(128, 8), 256, 0, stream>>>(xproj_pad, Wt_conv, conv_b,
      xconv_pad, nullptr, 3072, 1024, (long)SEQP * 1024, 3072, 1024, (long)SEQP * 1024, 1);
  // x_conv_out = conv(x_conv, cl)             [3072 -> 1024, padded]
  gemm_k<0><<<dim3(128, 8), 256, 0, stream>>>(xconv_pad, Wt_cl, cl_b,
      xco_pad, nullptr, 3072, 1024, (long)SEQP * 1024, 3072, 1024, (long)SEQP * 1024, 1);
  // delta_pre = conv(xco, fc1)                [3072 -> 1024, unpadded; aliases xconv]
  f16* delta_pre = xconv_pad;
  gemm_k<0><<<dim3(128, 8), 256, 0, stream>>>(xco_pad, Wt_fc1, fc1_b,
      delta_pre, nullptr, 3072, 1024, (long)SEQP * 1024, 3072, 1024, (long)SEQ * 1024, 0);
  // Bm|Cm split-K: grid (128 rows, 1, 8 k-slices) = 1024 blocks, 6 iters each
  gemm_k<6><<<dim3(128, 1, 8), 256, 0, stream>>>(xco_pad, Wt_fc23, b_fc23,
      bmcmF, nullptr, 384, 1024, (long)SEQP * 1024, 3072, 32, (long)SEQ * 32, 0);
  // prod = xco * softplus(delta) * cb * xres  [padded; aliases xproj]
  f16* prod_pad = xproj_pad;
  combine_k<<<16384, 256, 0, stream>>>(delta_pre, xco_pad, bmcmF, xres, prod_pad);
  // out = conv(prod, out)                     [3072 -> 512, fp32 -> d_out]
  gemm_k<2><<<dim3(128, 4), 256, 0, stream>>>(prod_pad, Wt_out, out_b,
      d_out, nullptr, 3072, 1024, (long)SEQP * 1024, 3072, 512, (long)SEQ * 512, 0);
}